// Round 15
// baseline (616.227 us; speedup 1.0000x reference)
//
#include <hip/hip_runtime.h>

// B=16, C=2048, HID=256, HW=1024. fp32 I/O.
// Pipeline: wcvt (W->f16) ;
//           proj (f16 MFMA, 512 thr, A reg-staged from f32 X w/ transpose+prefetch,
//                 reads X ONCE; proj-Q writes FULL qf ch[0,2048) passthrough bit-exact) ;
//           scores (f16 GEMM, 2-phase dbuf, XCD-swizzled) ; softmax (f32 in, f16 A in-place) ;
//           av (f16 GEMM, 2-phase dbuf, V reg-staged from pf f32; no V16, no copy2).
#define NB   16
#define NC   2048
#define NHID 256
#define NHW  1024

using half2_t  = __attribute__((ext_vector_type(2))) _Float16;
using half4_t  = __attribute__((ext_vector_type(4))) _Float16;
using half8_t  = __attribute__((ext_vector_type(8))) _Float16;
using float4_t = __attribute__((ext_vector_type(4))) float;

#define OUT_BATCH_BYTES ((size_t)(4096u * 1024u) * 4u)   /* 16 MiB per batch in out */

// ---------------- async 16B global -> LDS ----------------
__device__ __forceinline__ void async_load16(const void* g, void* l) {
    __builtin_amdgcn_global_load_lds((__attribute__((address_space(1))) void*)g,
                                     (__attribute__((address_space(3))) void*)l, 16, 0, 0);
}

// Stage a [nrows x 64-half] tile (128 B rows), 256 threads: LDS linear dest, source
// pre-swizzled so LDS slot sw of row holds logical slot sw^(row&7).
template <int NROWS>
__device__ __forceinline__ void stage_async(const _Float16* __restrict__ src, size_t stride_h,
                                            _Float16* __restrict__ lds, int t) {
    #pragma unroll
    for (int i = 0; i < NROWS / 32; ++i) {
        const int o   = i * 4096 + t * 16;          // byte offset in tile
        const int row = o >> 7;                     // 128 B per row
        const int s   = ((o >> 4) & 7) ^ (row & 7); // logical slot for this LDS slot
        const _Float16* g = src + (size_t)row * stride_h + s * 8;
        async_load16(g, (char*)lds + o);
    }
}

// Same, 512 threads, 256 rows (proj B-tile).
__device__ __forceinline__ void stage_async512(const _Float16* __restrict__ src, size_t stride_h,
                                               _Float16* __restrict__ lds, int t) {
    #pragma unroll
    for (int i = 0; i < 4; ++i) {
        const int o   = i * 8192 + t * 16;
        const int row = o >> 7;
        const int s   = ((o >> 4) & 7) ^ (row & 7);
        const _Float16* g = src + (size_t)row * stride_h + s * 8;
        async_load16(g, (char*)lds + o);
    }
}

// Fragment read with the same involution.
__device__ __forceinline__ half8_t frag_read(const _Float16* __restrict__ lds, int row, int kk, int quad) {
    const int s = (kk * 4 + quad) ^ (row & 7);
    return *(const half8_t*)((const char*)lds + row * 128 + s * 16);
}

#define ACC_INIT(acc) \
    _Pragma("unroll") for (int i_ = 0; i_ < 4; ++i_) \
    _Pragma("unroll") for (int j_ = 0; j_ < 4; ++j_) \
    _Pragma("unroll") for (int r_ = 0; r_ < 4; ++r_) acc[i_][j_][r_] = 0.f;

// ---------------- W f32[256][2048] -> f16 ----------------
__global__ __launch_bounds__(256) void wcvt_kernel(const float* __restrict__ W, _Float16* __restrict__ W16) {
    const int idx = (blockIdx.x * 256 + threadIdx.x) * 8;
    float4 a = *(const float4*)(W + idx);
    float4 c = *(const float4*)(W + idx + 4);
    half8_t h;
    h[0] = (_Float16)a.x; h[1] = (_Float16)a.y; h[2] = (_Float16)a.z; h[3] = (_Float16)a.w;
    h[4] = (_Float16)c.x; h[5] = (_Float16)c.y; h[6] = (_Float16)c.z; h[7] = (_Float16)c.w;
    *(half8_t*)(W16 + idx) = h;
}

// ---------------- proj: Q^T/K^T[hw][hid=256] = X^T W^T + b ; K=C=2048, BM=64, BN=256 ----------------
// 512 threads, 8 waves (2 hw x 4 hid of 32x64 subtiles). grid (16 hw-tiles, 1, 32 = which*16+b).
// A reg-staged from f32 X[c][hw] w/ in-register transpose; next step's X loads issued
// before the barrier so their latency drains concurrently with the W16 global_load_lds.
// which==0: writes FULL qf ch[0,2048) passthrough (bit-exact f32) to out-lo[0,8M).
__global__ __launch_bounds__(512, 4) void proj16_kernel(
    const float* __restrict__ qf, const float* __restrict__ pf,
    const _Float16* __restrict__ W16, const float* __restrict__ bias,
    _Float16* __restrict__ Q16, _Float16* __restrict__ K16,
    float* __restrict__ out) {
    __shared__ __attribute__((aligned(16))) _Float16 As[64 * 72];   // [hw][c], padded rows
    __shared__ __attribute__((aligned(16))) _Float16 Bs[256 * 64];  // swizzled, 32 KiB
    const int z = blockIdx.z, which = z >> 4, b = z & 15;
    const float* X = (which ? pf : qf) + (size_t)b * NC * NHW;
    float* passq = (float*)((char*)out + (size_t)b * OUT_BATCH_BYTES);  // ch c at passq + c*NHW
    _Float16* O = (which ? K16 : Q16) + (size_t)b * NHW * NHID;
    const int m0 = blockIdx.x * 64;   // hw
    const int t = threadIdx.x;
    const int l = t & 63, quad = l >> 4, l15 = l & 15;
    const int w = t >> 6;
    const int wr = (w >> 2) * 32;     // hw subtile {0,32}
    const int wc = (w & 3) * 64;      // hid subtile {0,64,128,192}
    const int j  = t & 15;            // hw-group (4 hw) for staging
    const int gs = t >> 4;            // c-pair group [0,32) for staging

    float4_t acc[2][4];
    #pragma unroll
    for (int i = 0; i < 2; ++i)
        #pragma unroll
        for (int jj = 0; jj < 4; ++jj)
            #pragma unroll
            for (int r = 0; r < 4; ++r) acc[i][jj][r] = 0.f;

    // prologue: first K-step's X rows
    const float* X0 = X + (size_t)(gs * 2) * NHW + m0 + j * 4;
    float4 x0 = *(const float4*)X0;
    float4 x1 = *(const float4*)(X0 + NHW);

    for (int k0 = 0; k0 < NC; k0 += 64) {
        // --- stage B: W16 tile, async swizzled (completion drains at the barrier) ---
        stage_async512(W16 + k0, NC, Bs, t);
        // --- passthrough (bit-exact f32, all channels) ---
        if (which == 0) {
            float* pq = passq + (size_t)(k0 + gs * 2) * NHW + m0 + j * 4;
            *(float4*)pq = x0;
            *(float4*)(pq + NHW) = x1;
        }
        // --- transpose-convert current X regs -> As[hw][c] ---
        #pragma unroll
        for (int e = 0; e < 4; ++e) {
            half2_t h2;
            h2[0] = (_Float16)((&x0.x)[e]);
            h2[1] = (_Float16)((&x1.x)[e]);
            *(half2_t*)(As + (j * 4 + e) * 72 + gs * 2) = h2;
        }
        // --- issue next step's X loads; latency hides under the barrier drain ---
        if (k0 + 64 < NC) {
            const float* Xn = X + (size_t)(k0 + 64 + gs * 2) * NHW + m0 + j * 4;
            x0 = *(const float4*)Xn;
            x1 = *(const float4*)(Xn + NHW);
        }
        __syncthreads();
        #pragma unroll
        for (int kk = 0; kk < 2; ++kk) {
            half8_t af[2], bf[4];
            #pragma unroll
            for (int i = 0; i < 2; ++i)
                af[i] = *(const half8_t*)(As + (wr + i * 16 + l15) * 72 + kk * 32 + quad * 8);
            #pragma unroll
            for (int jj = 0; jj < 4; ++jj)
                bf[jj] = frag_read(Bs, wc + jj * 16 + l15, kk, quad);
            #pragma unroll
            for (int i = 0; i < 2; ++i)
                #pragma unroll
                for (int jj = 0; jj < 4; ++jj)
                    acc[i][jj] = __builtin_amdgcn_mfma_f32_16x16x32_f16(af[i], bf[jj], acc[i][jj], 0, 0, 0);
        }
        __syncthreads();
    }
    #pragma unroll
    for (int jj = 0; jj < 4; ++jj) {
        const float bv = bias[wc + jj * 16 + l15];
        #pragma unroll
        for (int i = 0; i < 2; ++i)
            #pragma unroll
            for (int r = 0; r < 4; ++r) {
                int hw  = m0 + wr + i * 16 + quad * 4 + r;
                int hid = wc + jj * 16 + l15;
                O[(size_t)hw * NHID + hid] = (_Float16)(acc[i][jj][r] + bv);
            }
    }
}

// ---------------- scores: S[q1][q2] = Q^T . K^T ; K=256 ; 2-phase dbuf ; XCD-swizzled (8,8,16) ----------------
__global__ __launch_bounds__(256) void scores16_kernel(
    const _Float16* __restrict__ Q16, const _Float16* __restrict__ K16, float* __restrict__ S) {
    __shared__ __attribute__((aligned(16))) _Float16 As[2][8192];
    __shared__ __attribute__((aligned(16))) _Float16 Bs[2][8192];
    const int oid = blockIdx.x + blockIdx.y * 8 + blockIdx.z * 64;  // [0,1024)
    const int xcd = oid & 7, half = (oid >> 9) & 1, r = (oid >> 3) & 63;
    const int b = xcd * 2 + half;
    const int m0 = (r >> 3) * 128, n0 = (r & 7) * 128;
    const _Float16* A = Q16 + (size_t)b * NHW * NHID + (size_t)m0 * NHID;
    const _Float16* B = K16 + (size_t)b * NHW * NHID + (size_t)n0 * NHID;
    float* Sb = S + (size_t)b * NHW * NHW;
    const int t = threadIdx.x, l = t & 63, quad = l >> 4, l15 = l & 15, w = t >> 6;
    const int wr = (w >> 1) * 64, wc = (w & 1) * 64;
    float4_t acc[4][4];
    ACC_INIT(acc)

    stage_async<128>(A, NHID, As[0], t);
    stage_async<128>(B, NHID, Bs[0], t);
    __syncthreads();
    for (int kt = 0; kt < 4; ++kt) {            // K = 4 * 64
        const int cur = kt & 1, nxt = cur ^ 1;
        if (kt + 1 < 4) {
            stage_async<128>(A + (kt + 1) * 64, NHID, As[nxt], t);
            stage_async<128>(B + (kt + 1) * 64, NHID, Bs[nxt], t);
        }
        #pragma unroll
        for (int kk = 0; kk < 2; ++kk) {
            half8_t af[4], bf[4];
            #pragma unroll
            for (int i = 0; i < 4; ++i) af[i] = frag_read(As[cur], wr + i * 16 + l15, kk, quad);
            #pragma unroll
            for (int jj = 0; jj < 4; ++jj) bf[jj] = frag_read(Bs[cur], wc + jj * 16 + l15, kk, quad);
            #pragma unroll
            for (int i = 0; i < 4; ++i)
                #pragma unroll
                for (int jj = 0; jj < 4; ++jj)
                    acc[i][jj] = __builtin_amdgcn_mfma_f32_16x16x32_f16(af[i], bf[jj], acc[i][jj], 0, 0, 0);
        }
        __syncthreads();
    }
    #pragma unroll
    for (int i = 0; i < 4; ++i)
        #pragma unroll
        for (int jj = 0; jj < 4; ++jj)
            #pragma unroll
            for (int rr = 0; rr < 4; ++rr) {
                int q1 = m0 + wr + i * 16 + quad * 4 + rr;
                int q2 = n0 + wc + jj * 16 + l15;
                Sb[(size_t)q1 * NHW + q2] = acc[i][jj][rr];
            }
}

// ---------------- softmax: f32 row in, f16 row out in-place ----------------
__global__ __launch_bounds__(256) void softmax_kernel(float* __restrict__ S) {
    const int t = threadIdx.x, wave = t >> 6, lane = t & 63;
    float* row = S + ((size_t)blockIdx.x * 4 + wave) * NHW;
    float4 v[4];
    float mx = -1e30f;
    #pragma unroll
    for (int j = 0; j < 4; ++j) {
        v[j] = *(const float4*)(row + (lane << 2) + (j << 8));
        mx = fmaxf(mx, fmaxf(fmaxf(v[j].x, v[j].y), fmaxf(v[j].z, v[j].w)));
    }
    #pragma unroll
    for (int off = 32; off >= 1; off >>= 1) mx = fmaxf(mx, __shfl_xor(mx, off, 64));
    float s = 0.f;
    #pragma unroll
    for (int j = 0; j < 4; ++j) {
        v[j].x = __expf(v[j].x - mx); v[j].y = __expf(v[j].y - mx);
        v[j].z = __expf(v[j].z - mx); v[j].w = __expf(v[j].w - mx);
        s += v[j].x + v[j].y + v[j].z + v[j].w;
    }
    #pragma unroll
    for (int off = 32; off >= 1; off >>= 1) s += __shfl_xor(s, off, 64);
    const float inv = 1.0f / s;
    __syncthreads();  // all f32 loads complete before aliasing f16 stores
    _Float16* o = (_Float16*)row;
    #pragma unroll
    for (int j = 0; j < 4; ++j) {
        half4_t h;
        h[0] = (_Float16)(v[j].x * inv); h[1] = (_Float16)(v[j].y * inv);
        h[2] = (_Float16)(v[j].z * inv); h[3] = (_Float16)(v[j].w * inv);
        *(half4_t*)(o + (lane << 2) + (j << 8)) = h;
    }
}

// ---------------- AV: out[b,2048+c,q] = sum_k V[c][k] A16[q][k] ; K=1024 ; 2-phase dbuf ; XCD-swizzled (8,16,16) ----------------
// V reg-staged from pf f32 (convert at ds_write); B = A16 via global_load_lds. One barrier per K-step.
__global__ __launch_bounds__(256) void av16_kernel(
    const float* __restrict__ pf, const float* __restrict__ S, float* __restrict__ out) {
    __shared__ __attribute__((aligned(16))) _Float16 As[2][8192];
    __shared__ __attribute__((aligned(16))) _Float16 Bs[2][8192];
    const int oid = blockIdx.x + blockIdx.y * 8 + blockIdx.z * 128;  // [0,2048)
    const int xcd = oid & 7, half = (oid >> 10) & 1, r = (oid >> 3) & 127;
    const int b = xcd * 2 + half;
    const int m0 = (r >> 3) * 128;   // c
    const int n0 = (r & 7) * 128;    // q
    const float* Vb = pf + (size_t)b * NC * NHW;      // f32 [c][hw]
    const _Float16* A16 = (const _Float16*)(S + (size_t)b * NHW * NHW) + (size_t)n0 * 2048;
    float* Ob = out + (size_t)b * (2 * NC) * NHW + (size_t)NC * NHW;
    const int t = threadIdx.x, l = t & 63, quad = l >> 4, l15 = l & 15, w = t >> 6;
    const int wr = (w >> 1) * 64, wc = (w & 1) * 64;
    const int flat_r = t >> 3, flat_s = t & 7;        // staging: row (per i-chunk) and 16B slot

    float4_t acc[4][4];
    ACC_INIT(acc)

    float4 vr0[4], vr1[4];
    // loadV(kt): V rows for K-cols [kt*64, kt*64+64)
    #define LOADV(kt)                                                              \
        _Pragma("unroll")                                                          \
        for (int i = 0; i < 4; ++i) {                                              \
            const float* p = Vb + (size_t)(m0 + i * 32 + flat_r) * NHW + (kt) * 64 + flat_s * 8; \
            vr0[i] = *(const float4*)p;                                            \
            vr1[i] = *(const float4*)(p + 4);                                      \
        }
    // writeAs(buf): convert vr -> As[buf], swizzled slots
    #define WRITEAS(buf)                                                           \
        _Pragma("unroll")                                                          \
        for (int i = 0; i < 4; ++i) {                                              \
            const int rr = i * 32 + flat_r;                                        \
            half8_t h;                                                             \
            _Pragma("unroll")                                                      \
            for (int e = 0; e < 4; ++e) {                                          \
                h[e]     = (_Float16)((&vr0[i].x)[e]);                             \
                h[4 + e] = (_Float16)((&vr1[i].x)[e]);                             \
            }                                                                      \
            *(half8_t*)((char*)As[buf] + rr * 128 + ((flat_s ^ (rr & 7)) * 16)) = h; \
        }

    // prologue: tile 0 staged, tile 1's V in regs
    LOADV(0)
    stage_async<128>(A16, 2048, Bs[0], t);
    WRITEAS(0)
    LOADV(1)
    __syncthreads();

    for (int kt = 0; kt < 16; ++kt) {            // K = 16 * 64
        const int cur = kt & 1, nxt = cur ^ 1;
        if (kt + 1 < 16) {
            stage_async<128>(A16 + (kt + 1) * 64, 2048, Bs[nxt], t);
            WRITEAS(nxt)                          // vr holds tile kt+1
        }
        if (kt + 2 < 16) LOADV(kt + 2)
        #pragma unroll
        for (int kk = 0; kk < 2; ++kk) {
            half8_t af[4], bf[4];
            #pragma unroll
            for (int i = 0; i < 4; ++i) af[i] = frag_read(As[cur], wr + i * 16 + l15, kk, quad);
            #pragma unroll
            for (int jj = 0; jj < 4; ++jj) bf[jj] = frag_read(Bs[cur], wc + jj * 16 + l15, kk, quad);
            #pragma unroll
            for (int i = 0; i < 4; ++i)
                #pragma unroll
                for (int jj = 0; jj < 4; ++jj)
                    acc[i][jj] = __builtin_amdgcn_mfma_f32_16x16x32_f16(af[i], bf[jj], acc[i][jj], 0, 0, 0);
        }
        __syncthreads();
    }
    #undef LOADV
    #undef WRITEAS
    #pragma unroll
    for (int i = 0; i < 4; ++i)
        #pragma unroll
        for (int jj = 0; jj < 4; ++jj)
            #pragma unroll
            for (int rr = 0; rr < 4; ++rr) {
                int c = m0 + wr + i * 16 + quad * 4 + rr;
                int q = n0 + wc + jj * 16 + l15;
                Ob[(size_t)c * NHW + q] = acc[i][jj][rr];
            }
}

extern "C" void kernel_launch(void* const* d_in, const int* in_sizes, int n_in,
                              void* d_out, int out_size, void* d_ws, size_t ws_size,
                              hipStream_t stream) {
    const float* qf   = (const float*)d_in[0];
    const float* pf   = (const float*)d_in[1];
    const float* Wm   = (const float*)d_in[2];
    const float* bias = (const float*)d_in[3];
    float* out = (float*)d_out;

    // ws layout (80 MiB):
    //   [0,64M):  S [b][q1][q2] f32 (softmax rewrites rows as f16 A, stride 2048 halfs)
    //   [64,72M): Q16 [b][hw][hid]
    //   [72,80M): K16
    // out:
    //   per-batch lo [0,8M):  FULL qf ch[0,2048) passthrough, written by proj-Q (final data)
    //   batch0 hi [8M,9M):    W16 [hid][c] scratch (read only by proj; overwritten by av16)
    //   per-batch hi [8M,16M): aligned output, written by av16
    float*    S   = (float*)d_ws;
    _Float16* Q16 = (_Float16*)((char*)d_ws + ((size_t)64 << 20));
    _Float16* K16 = (_Float16*)((char*)d_ws + ((size_t)72 << 20));
    _Float16* W16 = (_Float16*)((char*)out + ((size_t)8 << 20));

    wcvt_kernel<<<256, 256, 0, stream>>>(Wm, W16);
    proj16_kernel<<<dim3(16, 1, 32), 512, 0, stream>>>(qf, pf, W16, bias, Q16, K16, out);
    scores16_kernel<<<dim3(8, 8, 16), 256, 0, stream>>>(Q16, K16, S);
    softmax_kernel<<<NB * 256, 256, 0, stream>>>(S);
    av16_kernel<<<dim3(8, 16, 16), 256, 0, stream>>>(pf, S, out);
}